// Round 5
// baseline (278.018 us; speedup 1.0000x reference)
//
#include <hip/hip_runtime.h>
#include <hip/hip_bf16.h>
#include <cstdint>

// SimVQ forward: b=8, n=1024 (R=8192 rows), dim=512, codes C=4096.
// Outputs flat f32: rotated [8192*512], indices-as-float [8192], loss [1].

#define R_ROWS 8192
#define DIM    512
#define NCODES 4096
#define BK     16
#define MARGIN      2.0e-3f
#define TILE_MARGIN 3.0e-3f

typedef __attribute__((ext_vector_type(8))) short bf16x8;
typedef __attribute__((ext_vector_type(4))) float f32x4;
typedef __attribute__((ext_vector_type(8))) unsigned short ushort8;

__device__ __forceinline__ void gload_lds16(const void* g, void* l) {
    __builtin_amdgcn_global_load_lds(
        (const __attribute__((address_space(1))) void*)g,
        (__attribute__((address_space(3))) void*)l, 16, 0, 0);
}

// ---------------- generic f32 NT GEMM (A[M][K] * B[N][K]^T) -----------------
template<int BM, int BN, int TM, int TN, bool ARGMIN>
__launch_bounds__(256)
__global__ void gemm_nt(const float* __restrict__ A, const float* __restrict__ Bm,
                        float* __restrict__ Cout,
                        const float* __restrict__ rowAdd, const float* __restrict__ colAdd,
                        float* __restrict__ pVal, int* __restrict__ pIdx,
                        int M, int N, int K) {
    constexpr int THREADS = (BM / TM) * (BN / TN);
    constexpr int PAD = 4;
    __shared__ float As[BK][BM + PAD];
    __shared__ float Bs[BK][BN + PAD];

    const int tid = threadIdx.x;
    const int tx = tid % (BN / TN);
    const int ty = tid / (BN / TN);
    const int rowBase = blockIdx.y * BM;
    const int colBase = blockIdx.x * BN;

    float acc[TM][TN];
#pragma unroll
    for (int i = 0; i < TM; i++)
#pragma unroll
        for (int j = 0; j < TN; j++) acc[i][j] = 0.f;

    constexpr int A_F4 = BM * BK / 4;
    constexpr int B_F4 = BN * BK / 4;
    const int nK = K / BK;

    for (int kt = 0; kt < nK; ++kt) {
        const int k0 = kt * BK;
#pragma unroll
        for (int f = 0; f < A_F4 / THREADS; ++f) {
            int e = tid + f * THREADS;
            int row = e >> 2;
            int kq = e & 3;
            float4 v = *reinterpret_cast<const float4*>(
                &A[(size_t)(rowBase + row) * K + k0 + kq * 4]);
            As[kq * 4 + 0][row] = v.x; As[kq * 4 + 1][row] = v.y;
            As[kq * 4 + 2][row] = v.z; As[kq * 4 + 3][row] = v.w;
        }
#pragma unroll
        for (int f = 0; f < B_F4 / THREADS; ++f) {
            int e = tid + f * THREADS;
            int row = e >> 2;
            int kq = e & 3;
            float4 v = *reinterpret_cast<const float4*>(
                &Bm[(size_t)(colBase + row) * K + k0 + kq * 4]);
            Bs[kq * 4 + 0][row] = v.x; Bs[kq * 4 + 1][row] = v.y;
            Bs[kq * 4 + 2][row] = v.z; Bs[kq * 4 + 3][row] = v.w;
        }
        __syncthreads();

#pragma unroll
        for (int k = 0; k < BK; k++) {
            float a[TM], b[TN];
#pragma unroll
            for (int i4 = 0; i4 < TM / 4; i4++) {
                float4 v = *reinterpret_cast<const float4*>(&As[k][ty * TM + i4 * 4]);
                a[i4 * 4 + 0] = v.x; a[i4 * 4 + 1] = v.y;
                a[i4 * 4 + 2] = v.z; a[i4 * 4 + 3] = v.w;
            }
#pragma unroll
            for (int j4 = 0; j4 < TN / 4; j4++) {
                float4 v = *reinterpret_cast<const float4*>(&Bs[k][tx * TN + j4 * 4]);
                b[j4 * 4 + 0] = v.x; b[j4 * 4 + 1] = v.y;
                b[j4 * 4 + 2] = v.z; b[j4 * 4 + 3] = v.w;
            }
#pragma unroll
            for (int i = 0; i < TM; i++)
#pragma unroll
                for (int j = 0; j < TN; j++) acc[i][j] = fmaf(a[i], b[j], acc[i][j]);
        }
        __syncthreads();
    }

    if constexpr (!ARGMIN) {
#pragma unroll
        for (int i = 0; i < TM; i++) {
#pragma unroll
            for (int j4 = 0; j4 < TN / 4; j4++) {
                float4 v = make_float4(acc[i][j4 * 4 + 0], acc[i][j4 * 4 + 1],
                                       acc[i][j4 * 4 + 2], acc[i][j4 * 4 + 3]);
                *reinterpret_cast<float4*>(
                    &Cout[(size_t)(rowBase + ty * TM + i) * N + colBase + tx * TN + j4 * 4]) = v;
            }
        }
    } else {
        constexpr int TX = BN / TN;
        __shared__ float rV[BM][TX + 1];
        __shared__ int   rI[BM][TX + 1];
        float xn[TM];
#pragma unroll
        for (int i = 0; i < TM; i++) xn[i] = rowAdd[rowBase + ty * TM + i];
        float cn[TN];
#pragma unroll
        for (int j = 0; j < TN; j++) cn[j] = colAdd[colBase + tx * TN + j];

#pragma unroll
        for (int i = 0; i < TM; i++) {
            float bv = 3.402823466e38f; int bi = 0;
#pragma unroll
            for (int j = 0; j < TN; j++) {
                float s = xn[i] + cn[j] - 2.f * acc[i][j];
                if (s < bv) { bv = s; bi = colBase + tx * TN + j; }
            }
            rV[ty * TM + i][tx] = bv;
            rI[ty * TM + i][tx] = bi;
        }
        __syncthreads();
        if (tid < BM) {
            float bv = 3.402823466e38f; int bi = 0;
#pragma unroll
            for (int t = 0; t < TX; t++) {
                float v = rV[tid][t];
                if (v < bv) { bv = v; bi = rI[tid][t]; }
            }
            int gr = rowBase + tid;
            pVal[(size_t)gr * gridDim.x + blockIdx.x] = bv;
            pIdx[(size_t)gr * gridDim.x + blockIdx.x] = bi;
        }
    }
}

// ------------- per-row sum of squares (wave per row, D=512) -----------------
__global__ void rowsumsq(const float* __restrict__ src, float* __restrict__ dst, int nRows) {
    int gw = (blockIdx.x * blockDim.x + threadIdx.x) >> 6;
    int lane = threadIdx.x & 63;
    if (gw >= nRows) return;
    const float4* s4 = reinterpret_cast<const float4*>(src + (size_t)gw * DIM);
    float4 a = s4[lane];
    float4 b = s4[lane + 64];
    float s = a.x * a.x + a.y * a.y + a.z * a.z + a.w * a.w
            + b.x * b.x + b.y * b.y + b.z * b.z + b.w * b.w;
#pragma unroll
    for (int o = 32; o; o >>= 1) s += __shfl_xor(s, o);
    if (lane == 0) dst[gw] = s;
}

// ------------- split f32 -> bf16 hi + bf16 lo (8 elems / thread) ------------
__global__ void split_bf16(const float* __restrict__ src, ushort* __restrict__ hi,
                           ushort* __restrict__ lo, int n8) {
    int t = blockIdx.x * blockDim.x + threadIdx.x;
    if (t >= n8) return;
    float4 a = reinterpret_cast<const float4*>(src)[(size_t)t * 2];
    float4 b = reinterpret_cast<const float4*>(src)[(size_t)t * 2 + 1];
    float v[8] = {a.x, a.y, a.z, a.w, b.x, b.y, b.z, b.w};
    ushort8 h, l;
#pragma unroll
    for (int e = 0; e < 8; ++e) {
        __hip_bfloat16 hb = __float2bfloat16(v[e]);
        float hf = __bfloat162float(hb);
        __hip_bfloat16 lb = __float2bfloat16(v[e] - hf);
        h[e] = *reinterpret_cast<unsigned short*>(&hb);
        l[e] = *reinterpret_cast<unsigned short*>(&lb);
    }
    reinterpret_cast<ushort8*>(hi)[t] = h;
    reinterpret_cast<ushort8*>(lo)[t] = l;
}

// ================= 256x256 8-phase MFMA split-bf16 score GEMM ================
// Effective GEMM: [8192 x 1536] * [4096 x 1536]^T where
//   A' = [xh | xh | xl],  B' = [ch | cl | ch]  ->  xh.ch + xh.cl + xl.ch
// 24 K-tiles of 64. 8 waves (2M x 4N). LDS 128 KiB double-buffered: 2 buf x
// (A,B) x 2 K-half x 16KB; each half = 256 rows x 32 elems, rows 64B wide.
// BANK-CONFLICT-FREE LAYOUT: within each 64B row, the four 16B g-chunks are
// stored at slot g' = g ^ ((row>>1)&3). A 16-lane fragment-read group (fixed
// g, 16 consecutive rows) then touches 8 distinct 16B columns, 2 rows each
// = 2 requests/bank, the hardware minimum (2-way aliasing is free, m136).
// The DMA dest stays linear; the per-lane GLOBAL source shuffles g within
// the same 64B row (coalescing preserved). Same XOR on read = involution.
// vmcnt ledger identical to round 4 (verified passing).

#define LDSOFF(BUF, ISB, KH) ((BUF) * 65536 + (ISB) * 32768 + (KH) * 16384)

__device__ __forceinline__ bf16x8 read_frag(const char* half_base, int row, int g) {
    int gp = g ^ ((row >> 1) & 3);
    return *reinterpret_cast<const bf16x8*>(half_base + row * 64 + gp * 16);
}

// stage one 16KB K-half (256 rows x 32 elems bf16) into LDS; linear dest,
// per-lane source picks the g-chunk that belongs at this lane's slot.
__device__ __forceinline__ void stage_half(const ushort* __restrict__ src, int rowBase,
                                           int segElem, char* ldsBase, int tid) {
#pragma unroll
    for (int i = 0; i < 2; ++i) {
        int o = i * 8192 + tid * 16;          // linear LDS slot this lane fills
        int row = o >> 6;
        int gp  = (o >> 4) & 3;
        int g   = gp ^ ((row >> 1) & 3);
        const char* gsrc = (const char*)src + (size_t)(rowBase + row) * 1024
                         + (size_t)segElem * 2 + g * 16;
        gload_lds16(gsrc, ldsBase + i * 8192 + (tid >> 6) * 1024);
    }
}

#define STAGE(STKT, STISB, STKH) do {                                          \
    int sk_ = (STKT) >= 24 ? (STKT) - 24 : (STKT);                             \
    int seg_ = sk_ >> 3; int se_ = ((sk_ & 7) << 6) + (STKH) * 32;             \
    const ushort* sp_ = (STISB) ? ((seg_ == 1) ? cl : ch)                      \
                                : ((seg_ == 2) ? xl : xh);                     \
    int rb_ = (STISB) ? colBase : rowBase;                                     \
    stage_half(sp_, rb_, se_, ldsc + LDSOFF((sk_ & 1), (STISB), (STKH)), tid); \
} while (0)

// MH=0 phase: loads A-frags (lower 64 rows of wave's 128) AND B-frags.
#define PHASE_A(BUF, KS, STKT, STISB, STKH) do {                               \
    __builtin_amdgcn_sched_barrier(0);                                         \
    _Pragma("unroll")                                                          \
    for (int m_ = 0; m_ < 4; ++m_)                                             \
        af_[m_] = read_frag(ldsc + LDSOFF((BUF), 0, (KS)),                     \
                            wr * 128 + m_ * 16 + c15, g);                      \
    _Pragma("unroll")                                                          \
    for (int n_ = 0; n_ < 4; ++n_)                                             \
        bf_[n_] = read_frag(ldsc + LDSOFF((BUF), 1, (KS)),                     \
                            wc * 64 + n_ * 16 + c15, g);                       \
    STAGE((STKT), (STISB), (STKH));                                            \
    __builtin_amdgcn_sched_barrier(0);                                         \
    __builtin_amdgcn_s_barrier();                                              \
    asm volatile("s_waitcnt lgkmcnt(0)");                                      \
    __builtin_amdgcn_sched_barrier(0);                                         \
    __builtin_amdgcn_s_setprio(1);                                             \
    _Pragma("unroll")                                                          \
    for (int m_ = 0; m_ < 4; ++m_)                                             \
        _Pragma("unroll")                                                      \
        for (int n_ = 0; n_ < 4; ++n_)                                         \
            acc[m_][n_] = __builtin_amdgcn_mfma_f32_16x16x32_bf16(             \
                af_[m_], bf_[n_], acc[m_][n_], 0, 0, 0);                       \
    __builtin_amdgcn_s_setprio(0);                                             \
    __builtin_amdgcn_sched_barrier(0);                                         \
    asm volatile("s_waitcnt vmcnt(8)");                                        \
    __builtin_amdgcn_sched_barrier(0);                                         \
    __builtin_amdgcn_s_barrier();                                              \
} while (0)

// MH=1 phase: loads only A-frags (upper 64 rows); reuses bf_ from PHASE_A.
#define PHASE_B(BUF, KS, STKT, STISB, STKH) do {                               \
    __builtin_amdgcn_sched_barrier(0);                                         \
    _Pragma("unroll")                                                          \
    for (int m_ = 0; m_ < 4; ++m_)                                             \
        af_[m_] = read_frag(ldsc + LDSOFF((BUF), 0, (KS)),                     \
                            wr * 128 + 64 + m_ * 16 + c15, g);                 \
    STAGE((STKT), (STISB), (STKH));                                            \
    __builtin_amdgcn_sched_barrier(0);                                         \
    __builtin_amdgcn_s_barrier();                                              \
    asm volatile("s_waitcnt lgkmcnt(0)");                                      \
    __builtin_amdgcn_sched_barrier(0);                                         \
    __builtin_amdgcn_s_setprio(1);                                             \
    _Pragma("unroll")                                                          \
    for (int m_ = 0; m_ < 4; ++m_)                                             \
        _Pragma("unroll")                                                      \
        for (int n_ = 0; n_ < 4; ++n_)                                         \
            acc[4 + m_][n_] = __builtin_amdgcn_mfma_f32_16x16x32_bf16(         \
                af_[m_], bf_[n_], acc[4 + m_][n_], 0, 0, 0);                   \
    __builtin_amdgcn_s_setprio(0);                                             \
    __builtin_amdgcn_sched_barrier(0);                                         \
    asm volatile("s_waitcnt vmcnt(8)");                                        \
    __builtin_amdgcn_sched_barrier(0);                                         \
    __builtin_amdgcn_s_barrier();                                              \
} while (0)

__launch_bounds__(512, 2)
__global__ void score_mfma8(const ushort* __restrict__ xh, const ushort* __restrict__ xl,
                            const ushort* __restrict__ ch, const ushort* __restrict__ cl,
                            const float* __restrict__ xn2, const float* __restrict__ cn2,
                            float* __restrict__ pV1, float* __restrict__ pV2,
                            int* __restrict__ pI1) {
    __shared__ __align__(16) ushort LDSarr[65536];   // 128 KiB
    char* ldsc = (char*)LDSarr;

    int bid = blockIdx.x;                    // 512 blocks, 512 % 8 == 0
    int swz = (bid & 7) * 64 + (bid >> 3);   // XCD-aware
    int tileN = swz & 15;                    // 16 N tiles (4096/256)
    int tileM = swz >> 4;                    // 32 M tiles (8192/256)
    int rowBase = tileM * 256, colBase = tileN * 256;

    int tid = threadIdx.x, lane = tid & 63, w = tid >> 6;
    int wr = w >> 2, wc = w & 3;             // 2M x 4N wave grid
    int g = lane >> 4, c15 = lane & 15;

    f32x4 acc[8][4];
#pragma unroll
    for (int m = 0; m < 8; m++)
#pragma unroll
        for (int n = 0; n < 4; n++) acc[m][n] = (f32x4){0.f, 0.f, 0.f, 0.f};

    bf16x8 af_[4], bf_[4];

    // prologue: T0 all 4 halves + T1 Kh0 halves (stream order) = 12 instrs
    STAGE(0, 0, 0); STAGE(0, 1, 0); STAGE(0, 0, 1); STAGE(0, 1, 1);
    STAGE(1, 0, 0); STAGE(1, 1, 0);
    __builtin_amdgcn_sched_barrier(0);
    asm volatile("s_waitcnt vmcnt(8)");
    __builtin_amdgcn_sched_barrier(0);
    __builtin_amdgcn_s_barrier();

    for (int kt = 0; kt < 24; ++kt) {
        int buf = kt & 1;
        PHASE_A(buf, 0, kt + 1, 0, 1);   // stage A(kt+1).Kh1
        PHASE_B(buf, 0, kt + 1, 1, 1);   // stage B(kt+1).Kh1
        PHASE_A(buf, 1, kt + 2, 0, 0);   // stage A(kt+2).Kh0
        PHASE_B(buf, 1, kt + 2, 1, 0);   // stage B(kt+2).Kh0
    }

    __syncthreads();   // full drain; LDS reused for reduction below

    // epilogue: score = xn2[row] + cn2[col] - 2*dot ; per-row (min1, idx1, min2)
    float* rv1 = (float*)ldsc;            // [256][4]
    float* rv2 = rv1 + 1024;              // [256][4]
    int*   ri1 = (int*)(rv1 + 2048);      // [256][4]

    float cnv[4];
#pragma unroll
    for (int n = 0; n < 4; ++n) cnv[n] = cn2[colBase + wc * 64 + n * 16 + c15];

#pragma unroll
    for (int m = 0; m < 8; ++m) {
#pragma unroll
        for (int j = 0; j < 4; ++j) {
            int rl = wr * 128 + m * 16 + g * 4 + j;
            float xn = xn2[rowBase + rl];
            float v1 = 3.402823466e38f, v2 = 3.402823466e38f; int i1 = 0x7fffffff;
#pragma unroll
            for (int n = 0; n < 4; ++n) {
                float s = xn + cnv[n] - 2.f * acc[m][n][j];
                int ci = colBase + wc * 64 + n * 16 + c15;
                if (s < v1 || (s == v1 && ci < i1)) { v2 = v1; v1 = s; i1 = ci; }
                else if (s < v2) v2 = s;
            }
#pragma unroll
            for (int off = 1; off < 16; off <<= 1) {
                float ov1 = __shfl_xor(v1, off);
                int   oi1 = __shfl_xor(i1, off);
                float ov2 = __shfl_xor(v2, off);
                if (ov1 < v1 || (ov1 == v1 && oi1 < i1)) {
                    v2 = fminf(v1, ov2); v1 = ov1; i1 = oi1;
                } else {
                    v2 = fminf(v2, ov1);
                }
            }
            if (c15 == 0) {
                rv1[rl * 4 + wc] = v1; rv2[rl * 4 + wc] = v2; ri1[rl * 4 + wc] = i1;
            }
        }
    }
    __syncthreads();
    if (tid < 256) {
        float v1 = 3.402823466e38f, v2 = 3.402823466e38f; int i1 = 0x7fffffff;
#pragma unroll
        for (int t = 0; t < 4; ++t) {
            float a1 = rv1[tid * 4 + t], a2 = rv2[tid * 4 + t];
            int   ai = ri1[tid * 4 + t];
            if (a1 < v1 || (a1 == v1 && ai < i1)) { v2 = fminf(v1, a2); v1 = a1; i1 = ai; }
            else { v2 = fminf(v2, a1); }
        }
        size_t o = (size_t)(rowBase + tid) * 16 + tileN;
        pV1[o] = v1; pV2[o] = v2; pI1[o] = i1;
    }
}

// ------------- combine per-tile partials -> idx + near-tie flag -------------
__global__ void combine_flag(const float* __restrict__ pV1, const float* __restrict__ pV2,
                             const int* __restrict__ pI1,
                             int* __restrict__ idx, float* __restrict__ idxF,
                             int* __restrict__ flag, float* __restrict__ vminOut) {
    int r = blockIdx.x * blockDim.x + threadIdx.x;
    if (r >= R_ROWS) return;
    float v1 = 3.402823466e38f, v2 = 3.402823466e38f; int i1 = 0x7fffffff;
    for (int t = 0; t < 16; ++t) {
        float a1 = pV1[(size_t)r * 16 + t];
        float a2 = pV2[(size_t)r * 16 + t];
        int   ai = pI1[(size_t)r * 16 + t];
        if (a1 < v1 || (a1 == v1 && ai < i1)) { v2 = fminf(v1, a2); v1 = a1; i1 = ai; }
        else { v2 = fminf(v2, a1); }
    }
    idx[r] = i1;
    idxF[r] = (float)i1;
    vminOut[r] = v1;
    flag[r] = (v2 - v1 < MARGIN) ? 1 : 0;
}

// ------------- exact f32 re-score of near-tie rows (candidate tiles only) ---
__launch_bounds__(256)
__global__ void refine_rows(const float* __restrict__ x, const float* __restrict__ cb,
                            const float* __restrict__ xn2, const float* __restrict__ cn2,
                            const float* __restrict__ pV1, const float* __restrict__ vmin,
                            const int* __restrict__ flag,
                            int* __restrict__ idx, float* __restrict__ idxF) {
    int r = blockIdx.x;
    if (flag[r] == 0) return;

    __shared__ float xs[DIM];
    __shared__ float sv[256];
    __shared__ int   si[256];
    for (int i = threadIdx.x; i < DIM; i += 256) xs[i] = x[(size_t)r * DIM + i];
    __syncthreads();

    float xn = xn2[r];
    float thr = vmin[r] + TILE_MARGIN;
    float v1 = 3.402823466e38f; int i1 = 0x7fffffff;

    for (int t = 0; t < 16; ++t) {
        if (pV1[(size_t)r * 16 + t] > thr) continue;
        int c = t * 256 + threadIdx.x;
        const float4* cr = reinterpret_cast<const float4*>(cb + (size_t)c * DIM);
        float dot = 0.f;
#pragma unroll 8
        for (int k = 0; k < DIM / 4; ++k) {
            float4 cv = cr[k];
            dot = fmaf(xs[k * 4 + 0], cv.x, dot);
            dot = fmaf(xs[k * 4 + 1], cv.y, dot);
            dot = fmaf(xs[k * 4 + 2], cv.z, dot);
            dot = fmaf(xs[k * 4 + 3], cv.w, dot);
        }
        float s = xn + cn2[c] - 2.f * dot;
        if (s < v1 || (s == v1 && c < i1)) { v1 = s; i1 = c; }
    }
    sv[threadIdx.x] = v1; si[threadIdx.x] = i1;
    __syncthreads();
    for (int o = 128; o; o >>= 1) {
        if (threadIdx.x < o) {
            float ov = sv[threadIdx.x + o]; int oi = si[threadIdx.x + o];
            if (ov < sv[threadIdx.x] || (ov == sv[threadIdx.x] && oi < si[threadIdx.x])) {
                sv[threadIdx.x] = ov; si[threadIdx.x] = oi;
            }
        }
        __syncthreads();
    }
    if (threadIdx.x == 0) { idx[r] = si[0]; idxF[r] = (float)si[0]; }
}

// ------------- combine per-tile argmin partials (fallback path) -------------
__global__ void argmin_combine(const float* __restrict__ pVal, const int* __restrict__ pIdx,
                               int* __restrict__ idxOut, float* __restrict__ idxFloatOut,
                               int nTiles) {
    int r = blockIdx.x * blockDim.x + threadIdx.x;
    if (r >= R_ROWS) return;
    float bv = 3.402823466e38f; int bi = 0;
    for (int t = 0; t < nTiles; t++) {
        float v = pVal[(size_t)r * nTiles + t];
        if (v < bv) { bv = v; bi = pIdx[(size_t)r * nTiles + t]; }
    }
    idxOut[r] = bi;
    idxFloatOut[r] = (float)bi;
}

// ------------- rotation trick, one wave per row -----------------------------
__global__ void rotate_rows(const float* __restrict__ x, const float* __restrict__ cb,
                            const int* __restrict__ idx, float* __restrict__ out,
                            float* __restrict__ lossPartial) {
    int gw = (blockIdx.x * blockDim.x + threadIdx.x) >> 6;
    int lane = threadIdx.x & 63;
    if (gw >= R_ROWS) return;

    const float4* x4 = reinterpret_cast<const float4*>(x + (size_t)gw * DIM);
    float4 xa = x4[lane], xb = x4[lane + 64];
    int ci = idx[gw];
    const float4* q4 = reinterpret_cast<const float4*>(cb + (size_t)ci * DIM);
    float4 qa = q4[lane], qb = q4[lane + 64];

    float xe[8] = {xa.x, xa.y, xa.z, xa.w, xb.x, xb.y, xb.z, xb.w};
    float qe[8] = {qa.x, qa.y, qa.z, qa.w, qb.x, qb.y, qb.z, qb.w};

    auto wsum = [&](float v) {
#pragma unroll
        for (int o = 32; o; o >>= 1) v += __shfl_xor(v, o);
        return v;
    };

    float lx = 0.f, lq = 0.f, ld = 0.f;
#pragma unroll
    for (int e = 0; e < 8; e++) {
        lx += xe[e] * xe[e];
        lq += qe[e] * qe[e];
        float d = xe[e] - qe[e];
        ld += d * d;
    }
    float sx2 = wsum(lx);
    float sq2 = wsum(lq);
    float lp  = wsum(ld);

    float nx = sqrtf(sx2), nq = sqrtf(sq2);
    float inx = 1.f / fmaxf(nx, 1e-6f);
    float inq = 1.f / fmaxf(nq, 1e-6f);

    float ue[8], qh[8], we[8];
    float lw = 0.f;
#pragma unroll
    for (int e = 0; e < 8; e++) {
        ue[e] = xe[e] * inx;
        qh[e] = qe[e] * inq;
        we[e] = ue[e] + qh[e];
        lw += we[e] * we[e];
    }
    float sw2 = wsum(lw);
    float inw = 1.f / fmaxf(sqrtf(sw2), 1e-6f);

    float lew = 0.f, leu = 0.f;
#pragma unroll
    for (int e = 0; e < 8; e++) {
        we[e] *= inw;
        lew += xe[e] * we[e];
        leu += xe[e] * ue[e];
    }
    float ew = wsum(lew);
    float eu = wsum(leu);

    float scale = nq / fmaxf(nx, 1e-6f);
    float oe[8];
#pragma unroll
    for (int e = 0; e < 8; e++)
        oe[e] = (xe[e] - 2.f * ew * we[e] + 2.f * eu * qh[e]) * scale;

    float4* o4 = reinterpret_cast<float4*>(out + (size_t)gw * DIM);
    o4[lane]      = make_float4(oe[0], oe[1], oe[2], oe[3]);
    o4[lane + 64] = make_float4(oe[4], oe[5], oe[6], oe[7]);

    if (lane == 0) lossPartial[gw] = lp;
}

// ------------- final loss reduction -----------------------------------------
__global__ void loss_reduce(const float* __restrict__ lp, float* __restrict__ outScalar) {
    __shared__ float red[256];
    float s = 0.f;
    for (int i = threadIdx.x; i < R_ROWS; i += 256) s += lp[i];
    red[threadIdx.x] = s;
    __syncthreads();
    for (int o = 128; o; o >>= 1) {
        if (threadIdx.x < o) red[threadIdx.x] += red[threadIdx.x + o];
        __syncthreads();
    }
    if (threadIdx.x == 0)
        outScalar[0] = 1.25f * red[0] / (float)(R_ROWS * DIM);
}

extern "C" void kernel_launch(void* const* d_in, const int* in_sizes, int n_in,
                              void* d_out, int out_size, void* d_ws, size_t ws_size,
                              hipStream_t stream) {
    const float* x      = (const float*)d_in[0];   // [8192, 512]
    const float* frozen = (const float*)d_in[1];   // [4096, 512]
    const float* weight = (const float*)d_in[2];   // [512, 512]
    float* out = (float*)d_out;

    // ---- workspace layout (MFMA path) ----
    char* p = (char*)d_ws;
    float* cb  = (float*)p;            p += (size_t)NCODES * DIM * 4;
    ushort* xh = (ushort*)p;           p += (size_t)R_ROWS * DIM * 2;
    ushort* xl = (ushort*)p;           p += (size_t)R_ROWS * DIM * 2;
    ushort* ch = (ushort*)p;           p += (size_t)NCODES * DIM * 2;
    ushort* cl = (ushort*)p;           p += (size_t)NCODES * DIM * 2;
    float* cn2 = (float*)p;            p += NCODES * 4;
    float* xn2 = (float*)p;            p += R_ROWS * 4;
    float* pV1 = (float*)p;            p += (size_t)R_ROWS * 16 * 4;
    float* pV2 = (float*)p;            p += (size_t)R_ROWS * 16 * 4;
    int*   pI1 = (int*)p;              p += (size_t)R_ROWS * 16 * 4;
    int*   idx = (int*)p;              p += R_ROWS * 4;
    int*   flg = (int*)p;              p += R_ROWS * 4;
    float* vmn = (float*)p;            p += R_ROWS * 4;
    float* lp  = (float*)p;            p += R_ROWS * 4;
    size_t need = (size_t)(p - (char*)d_ws);

    // 1. codebook = frozen @ W^T : M=4096, N=512, K=512 (f32, exact)
    //    128x64 tile, 8x4 microtile, 256 threads, 256 blocks (1/CU).
    dim3 g1(DIM / 64, NCODES / 128);
    gemm_nt<128, 64, 8, 4, false><<<g1, 256, 0, stream>>>(
        frozen, weight, cb, nullptr, nullptr, nullptr, nullptr, NCODES, DIM, DIM);

    // 2. exact row norms
    rowsumsq<<<NCODES / 4, 256, 0, stream>>>(cb, cn2, NCODES);
    rowsumsq<<<R_ROWS / 4, 256, 0, stream>>>(x, xn2, R_ROWS);

    if (ws_size >= need) {
        // 3. split inputs into bf16 hi/lo
        split_bf16<<<(R_ROWS * DIM / 8) / 256, 256, 0, stream>>>(x, xh, xl, R_ROWS * DIM / 8);
        split_bf16<<<(NCODES * DIM / 8) / 256, 256, 0, stream>>>(cb, ch, cl, NCODES * DIM / 8);

        // 4. 8-phase 256^2 MFMA score GEMM + per-tile (min1, idx1, min2)
        score_mfma8<<<(R_ROWS / 256) * (NCODES / 256), 512, 0, stream>>>(
            xh, xl, ch, cl, xn2, cn2, pV1, pV2, pI1);

        // 5. combine + near-tie flag
        combine_flag<<<R_ROWS / 256, 256, 0, stream>>>(
            pV1, pV2, pI1, idx, out + (size_t)R_ROWS * DIM, flg, vmn);

        // 6. exact f32 re-score of flagged rows (candidate tiles only)
        refine_rows<<<R_ROWS, 256, 0, stream>>>(
            x, cb, xn2, cn2, pV1, vmn, flg, idx, out + (size_t)R_ROWS * DIM);
    } else {
        // fallback: proven f32 path
        float* fpV = (float*)((char*)d_ws + (size_t)NCODES * DIM * 4 + NCODES * 4 + R_ROWS * 4);
        int*   fpI = (int*)(fpV + (size_t)R_ROWS * 32);
        int*   fidx = (int*)(fpI + (size_t)R_ROWS * 32);
        float* flp = (float*)(fidx + R_ROWS);
        float* fcn2 = (float*)((char*)d_ws + (size_t)NCODES * DIM * 4);
        float* fxn2 = fcn2 + NCODES;
        rowsumsq<<<NCODES / 4, 256, 0, stream>>>(cb, fcn2, NCODES);
        rowsumsq<<<R_ROWS / 4, 256, 0, stream>>>(x, fxn2, R_ROWS);
        dim3 g2(NCODES / 128, R_ROWS / 128);
        gemm_nt<128, 128, 8, 8, true><<<g2, 256, 0, stream>>>(
            x, cb, nullptr, fxn2, fcn2, fpV, fpI, R_ROWS, NCODES, DIM);
        argmin_combine<<<R_ROWS / 256, 256, 0, stream>>>(
            fpV, fpI, fidx, out + (size_t)R_ROWS * DIM, NCODES / 128);
        rotate_rows<<<R_ROWS / 4, 256, 0, stream>>>(x, cb, fidx, out, flp);
        loss_reduce<<<1, 256, 0, stream>>>(flp, out + ((size_t)R_ROWS * DIM + R_ROWS));
        return;
    }

    // 7. rotation trick + loss
    rotate_rows<<<R_ROWS / 4, 256, 0, stream>>>(x, cb, idx, out, lp);
    loss_reduce<<<1, 256, 0, stream>>>(lp, out + ((size_t)R_ROWS * DIM + R_ROWS));
}

// Round 6
// 262.024 us; speedup vs baseline: 1.0610x; 1.0610x over previous
//
#include <hip/hip_runtime.h>
#include <hip/hip_bf16.h>
#include <cstdint>

// SimVQ forward: b=8, n=1024 (R=8192 rows), dim=512, codes C=4096.
// Outputs flat f32: rotated [8192*512], indices-as-float [8192], loss [1].

#define R_ROWS 8192
#define DIM    512
#define NCODES 4096
#define BK     16
#define MARGIN      2.0e-3f
#define TILE_MARGIN 3.0e-3f

typedef __attribute__((ext_vector_type(8))) short bf16x8;
typedef __attribute__((ext_vector_type(4))) float f32x4;
typedef __attribute__((ext_vector_type(8))) unsigned short ushort8;

__device__ __forceinline__ void gload_lds16(const void* g, void* l) {
    __builtin_amdgcn_global_load_lds(
        (const __attribute__((address_space(1))) void*)g,
        (__attribute__((address_space(3))) void*)l, 16, 0, 0);
}

// ---------------- generic f32 NT GEMM (A[M][K] * B[N][K]^T) -----------------
template<int BM, int BN, int TM, int TN, bool ARGMIN>
__launch_bounds__(256)
__global__ void gemm_nt(const float* __restrict__ A, const float* __restrict__ Bm,
                        float* __restrict__ Cout,
                        const float* __restrict__ rowAdd, const float* __restrict__ colAdd,
                        float* __restrict__ pVal, int* __restrict__ pIdx,
                        int M, int N, int K) {
    constexpr int THREADS = (BM / TM) * (BN / TN);
    constexpr int PAD = 4;
    __shared__ float As[BK][BM + PAD];
    __shared__ float Bs[BK][BN + PAD];

    const int tid = threadIdx.x;
    const int tx = tid % (BN / TN);
    const int ty = tid / (BN / TN);
    const int rowBase = blockIdx.y * BM;
    const int colBase = blockIdx.x * BN;

    float acc[TM][TN];
#pragma unroll
    for (int i = 0; i < TM; i++)
#pragma unroll
        for (int j = 0; j < TN; j++) acc[i][j] = 0.f;

    constexpr int A_F4 = BM * BK / 4;
    constexpr int B_F4 = BN * BK / 4;
    const int nK = K / BK;

    for (int kt = 0; kt < nK; ++kt) {
        const int k0 = kt * BK;
#pragma unroll
        for (int f = 0; f < A_F4 / THREADS; ++f) {
            int e = tid + f * THREADS;
            int row = e >> 2;
            int kq = e & 3;
            float4 v = *reinterpret_cast<const float4*>(
                &A[(size_t)(rowBase + row) * K + k0 + kq * 4]);
            As[kq * 4 + 0][row] = v.x; As[kq * 4 + 1][row] = v.y;
            As[kq * 4 + 2][row] = v.z; As[kq * 4 + 3][row] = v.w;
        }
#pragma unroll
        for (int f = 0; f < B_F4 / THREADS; ++f) {
            int e = tid + f * THREADS;
            int row = e >> 2;
            int kq = e & 3;
            float4 v = *reinterpret_cast<const float4*>(
                &Bm[(size_t)(colBase + row) * K + k0 + kq * 4]);
            Bs[kq * 4 + 0][row] = v.x; Bs[kq * 4 + 1][row] = v.y;
            Bs[kq * 4 + 2][row] = v.z; Bs[kq * 4 + 3][row] = v.w;
        }
        __syncthreads();

#pragma unroll
        for (int k = 0; k < BK; k++) {
            float a[TM], b[TN];
#pragma unroll
            for (int i4 = 0; i4 < TM / 4; i4++) {
                float4 v = *reinterpret_cast<const float4*>(&As[k][ty * TM + i4 * 4]);
                a[i4 * 4 + 0] = v.x; a[i4 * 4 + 1] = v.y;
                a[i4 * 4 + 2] = v.z; a[i4 * 4 + 3] = v.w;
            }
#pragma unroll
            for (int j4 = 0; j4 < TN / 4; j4++) {
                float4 v = *reinterpret_cast<const float4*>(&Bs[k][tx * TN + j4 * 4]);
                b[j4 * 4 + 0] = v.x; b[j4 * 4 + 1] = v.y;
                b[j4 * 4 + 2] = v.z; b[j4 * 4 + 3] = v.w;
            }
#pragma unroll
            for (int i = 0; i < TM; i++)
#pragma unroll
                for (int j = 0; j < TN; j++) acc[i][j] = fmaf(a[i], b[j], acc[i][j]);
        }
        __syncthreads();
    }

    if constexpr (!ARGMIN) {
#pragma unroll
        for (int i = 0; i < TM; i++) {
#pragma unroll
            for (int j4 = 0; j4 < TN / 4; j4++) {
                float4 v = make_float4(acc[i][j4 * 4 + 0], acc[i][j4 * 4 + 1],
                                       acc[i][j4 * 4 + 2], acc[i][j4 * 4 + 3]);
                *reinterpret_cast<float4*>(
                    &Cout[(size_t)(rowBase + ty * TM + i) * N + colBase + tx * TN + j4 * 4]) = v;
            }
        }
    } else {
        constexpr int TX = BN / TN;
        __shared__ float rV[BM][TX + 1];
        __shared__ int   rI[BM][TX + 1];
        float xn[TM];
#pragma unroll
        for (int i = 0; i < TM; i++) xn[i] = rowAdd[rowBase + ty * TM + i];
        float cn[TN];
#pragma unroll
        for (int j = 0; j < TN; j++) cn[j] = colAdd[colBase + tx * TN + j];

#pragma unroll
        for (int i = 0; i < TM; i++) {
            float bv = 3.402823466e38f; int bi = 0;
#pragma unroll
            for (int j = 0; j < TN; j++) {
                float s = xn[i] + cn[j] - 2.f * acc[i][j];
                if (s < bv) { bv = s; bi = colBase + tx * TN + j; }
            }
            rV[ty * TM + i][tx] = bv;
            rI[ty * TM + i][tx] = bi;
        }
        __syncthreads();
        if (tid < BM) {
            float bv = 3.402823466e38f; int bi = 0;
#pragma unroll
            for (int t = 0; t < TX; t++) {
                float v = rV[tid][t];
                if (v < bv) { bv = v; bi = rI[tid][t]; }
            }
            int gr = rowBase + tid;
            pVal[(size_t)gr * gridDim.x + blockIdx.x] = bv;
            pIdx[(size_t)gr * gridDim.x + blockIdx.x] = bi;
        }
    }
}

// ------------- per-row sum of squares (wave per row, D=512) -----------------
__global__ void rowsumsq(const float* __restrict__ src, float* __restrict__ dst, int nRows) {
    int gw = (blockIdx.x * blockDim.x + threadIdx.x) >> 6;
    int lane = threadIdx.x & 63;
    if (gw >= nRows) return;
    const float4* s4 = reinterpret_cast<const float4*>(src + (size_t)gw * DIM);
    float4 a = s4[lane];
    float4 b = s4[lane + 64];
    float s = a.x * a.x + a.y * a.y + a.z * a.z + a.w * a.w
            + b.x * b.x + b.y * b.y + b.z * b.z + b.w * b.w;
#pragma unroll
    for (int o = 32; o; o >>= 1) s += __shfl_xor(s, o);
    if (lane == 0) dst[gw] = s;
}

// ------------- split f32 -> bf16 hi + bf16 lo (8 elems / thread) ------------
__global__ void split_bf16(const float* __restrict__ src, ushort* __restrict__ hi,
                           ushort* __restrict__ lo, int n8) {
    int t = blockIdx.x * blockDim.x + threadIdx.x;
    if (t >= n8) return;
    float4 a = reinterpret_cast<const float4*>(src)[(size_t)t * 2];
    float4 b = reinterpret_cast<const float4*>(src)[(size_t)t * 2 + 1];
    float v[8] = {a.x, a.y, a.z, a.w, b.x, b.y, b.z, b.w};
    ushort8 h, l;
#pragma unroll
    for (int e = 0; e < 8; ++e) {
        __hip_bfloat16 hb = __float2bfloat16(v[e]);
        float hf = __bfloat162float(hb);
        __hip_bfloat16 lb = __float2bfloat16(v[e] - hf);
        h[e] = *reinterpret_cast<unsigned short*>(&hb);
        l[e] = *reinterpret_cast<unsigned short*>(&lb);
    }
    reinterpret_cast<ushort8*>(hi)[t] = h;
    reinterpret_cast<ushort8*>(lo)[t] = l;
}

// ================= 256x256 8-phase MFMA split-bf16 score GEMM ================
// Effective GEMM: [8192 x 1536] * [4096 x 1536]^T where
//   A' = [xh | xh | xl],  B' = [ch | cl | ch]  ->  xh.ch + xh.cl + xl.ch
// 24 K-tiles of 64. 8 waves (2M x 4N). LDS 128 KiB: 2 buf x (A,B) x 2 KH x
// 16 KB; each half = 256 rows x 32 elems (64B rows), g-XOR bank swizzle
// (round-5 verified: conflicts 9.6e6 -> 1.5e5).
// COUNTED-vmcnt CADENCE (m201: vmcnt once per K-tile, never every phase):
//   stage slots per tile kt (1 half / phase, 2 thread-instrs each):
//     S1 (ph1): A(kt+1).KH1  -> other buffer (safe vs all current reads)
//     S2 (ph2): B(kt+2).KH0  -> current buf; B.KH0 last read ph1 (drained)
//     S3 (ph3): A(kt+2).KH0  -> current buf; A.KH0 last read ph2 (drained)
//     S4 (ph4): B(kt+2).KH1  -> current buf; B.KH1 last read ph3 (drained)
//   single vmcnt(6) at end of ph4: leaves exactly {S2,S3,S4} (3 halves)
//   pending; tile kt+1 consumes none of them, and each tile's 4 halves are
//   staged at slots {(kt-2).S2..S4, (kt-1).S1} => all landed at tile entry.
//   Prologue: 7 halves [A0.0 B0.0 A0.1 B0.1 | B1.0 A1.0 B1.1] + vmcnt(6)
//   leaves pending exactly {B1.0, A1.0, B1.1} = steady-state invariant.

#define LDSOFF(BUF, ISB, KH) ((BUF) * 65536 + (ISB) * 32768 + (KH) * 16384)

__device__ __forceinline__ bf16x8 read_frag(const char* half_base, int row, int g) {
    int gp = g ^ ((row >> 1) & 3);
    return *reinterpret_cast<const bf16x8*>(half_base + row * 64 + gp * 16);
}

// stage one 16KB K-half (256 rows x 32 elems bf16) into LDS; linear dest,
// per-lane source picks the g-chunk that belongs at this lane's slot.
__device__ __forceinline__ void stage_half(const ushort* __restrict__ src, int rowBase,
                                           int segElem, char* ldsBase, int tid) {
#pragma unroll
    for (int i = 0; i < 2; ++i) {
        int o = i * 8192 + tid * 16;          // linear LDS slot this lane fills
        int row = o >> 6;
        int gp  = (o >> 4) & 3;
        int g   = gp ^ ((row >> 1) & 3);
        const char* gsrc = (const char*)src + (size_t)(rowBase + row) * 1024
                         + (size_t)segElem * 2 + g * 16;
        gload_lds16(gsrc, ldsBase + i * 8192 + (tid >> 6) * 1024);
    }
}

#define STAGE(STKT, STISB, STKH) do {                                          \
    int sk_ = (STKT) >= 24 ? (STKT) - 24 : (STKT);                             \
    int seg_ = sk_ >> 3; int se_ = ((sk_ & 7) << 6) + (STKH) * 32;             \
    const ushort* sp_ = (STISB) ? ((seg_ == 1) ? cl : ch)                      \
                                : ((seg_ == 2) ? xl : xh);                     \
    int rb_ = (STISB) ? colBase : rowBase;                                     \
    stage_half(sp_, rb_, se_, ldsc + LDSOFF((sk_ & 1), (STISB), (STKH)), tid); \
} while (0)

// phase end: no vmcnt (counted cadence), just barrier
#define ENDP() do {                                                            \
    __builtin_amdgcn_s_barrier();                                              \
} while (0)
// K-tile end: single counted vmcnt(6) then barrier
#define ENDV6() do {                                                           \
    asm volatile("s_waitcnt vmcnt(6)");                                        \
    __builtin_amdgcn_sched_barrier(0);                                         \
    __builtin_amdgcn_s_barrier();                                              \
} while (0)

// MH=0 phase: loads A-frags (lower 64 rows of wave's 128) AND B-frags.
#define PHASE_A(BUF, KS, STKT, STISB, STKH) do {                               \
    __builtin_amdgcn_sched_barrier(0);                                         \
    _Pragma("unroll")                                                          \
    for (int m_ = 0; m_ < 4; ++m_)                                             \
        af_[m_] = read_frag(ldsc + LDSOFF((BUF), 0, (KS)),                     \
                            wr * 128 + m_ * 16 + c15, g);                      \
    _Pragma("unroll")                                                          \
    for (int n_ = 0; n_ < 4; ++n_)                                             \
        bf_[n_] = read_frag(ldsc + LDSOFF((BUF), 1, (KS)),                     \
                            wc * 64 + n_ * 16 + c15, g);                       \
    STAGE((STKT), (STISB), (STKH));                                            \
    __builtin_amdgcn_sched_barrier(0);                                         \
    __builtin_amdgcn_s_barrier();                                              \
    asm volatile("s_waitcnt lgkmcnt(0)");                                      \
    __builtin_amdgcn_sched_barrier(0);                                         \
    __builtin_amdgcn_s_setprio(1);                                             \
    _Pragma("unroll")                                                          \
    for (int m_ = 0; m_ < 4; ++m_)                                             \
        _Pragma("unroll")                                                      \
        for (int n_ = 0; n_ < 4; ++n_)                                         \
            acc[m_][n_] = __builtin_amdgcn_mfma_f32_16x16x32_bf16(             \
                af_[m_], bf_[n_], acc[m_][n_], 0, 0, 0);                       \
    __builtin_amdgcn_s_setprio(0);                                             \
    __builtin_amdgcn_sched_barrier(0);                                         \
} while (0)

// MH=1 phase: loads only A-frags (upper 64 rows); reuses bf_ from PHASE_A.
#define PHASE_B(BUF, KS, STKT, STISB, STKH) do {                               \
    __builtin_amdgcn_sched_barrier(0);                                         \
    _Pragma("unroll")                                                          \
    for (int m_ = 0; m_ < 4; ++m_)                                             \
        af_[m_] = read_frag(ldsc + LDSOFF((BUF), 0, (KS)),                     \
                            wr * 128 + 64 + m_ * 16 + c15, g);                 \
    STAGE((STKT), (STISB), (STKH));                                            \
    __builtin_amdgcn_sched_barrier(0);                                         \
    __builtin_amdgcn_s_barrier();                                              \
    asm volatile("s_waitcnt lgkmcnt(0)");                                      \
    __builtin_amdgcn_sched_barrier(0);                                         \
    __builtin_amdgcn_s_setprio(1);                                             \
    _Pragma("unroll")                                                          \
    for (int m_ = 0; m_ < 4; ++m_)                                             \
        _Pragma("unroll")                                                      \
        for (int n_ = 0; n_ < 4; ++n_)                                         \
            acc[4 + m_][n_] = __builtin_amdgcn_mfma_f32_16x16x32_bf16(         \
                af_[m_], bf_[n_], acc[4 + m_][n_], 0, 0, 0);                   \
    __builtin_amdgcn_s_setprio(0);                                             \
    __builtin_amdgcn_sched_barrier(0);                                         \
} while (0)

__launch_bounds__(512, 2)
__global__ void score_mfma8(const ushort* __restrict__ xh, const ushort* __restrict__ xl,
                            const ushort* __restrict__ ch, const ushort* __restrict__ cl,
                            const float* __restrict__ xn2, const float* __restrict__ cn2,
                            float* __restrict__ pV1, float* __restrict__ pV2,
                            int* __restrict__ pI1) {
    __shared__ __align__(16) ushort LDSarr[65536];   // 128 KiB
    char* ldsc = (char*)LDSarr;

    int bid = blockIdx.x;                    // 512 blocks, 512 % 8 == 0
    int swz = (bid & 7) * 64 + (bid >> 3);   // XCD-aware
    int tileN = swz & 15;                    // 16 N tiles (4096/256)
    int tileM = swz >> 4;                    // 32 M tiles (8192/256)
    int rowBase = tileM * 256, colBase = tileN * 256;

    int tid = threadIdx.x, lane = tid & 63, w = tid >> 6;
    int wr = w >> 2, wc = w & 3;             // 2M x 4N wave grid
    int g = lane >> 4, c15 = lane & 15;

    f32x4 acc[8][4];
#pragma unroll
    for (int m = 0; m < 8; m++)
#pragma unroll
        for (int n = 0; n < 4; n++) acc[m][n] = (f32x4){0.f, 0.f, 0.f, 0.f};

    bf16x8 af_[4], bf_[4];

    // prologue: T0 x4 + [B1.KH0, A1.KH0, B1.KH1] = 14 thread-instrs
    STAGE(0, 0, 0); STAGE(0, 1, 0); STAGE(0, 0, 1); STAGE(0, 1, 1);
    STAGE(1, 1, 0); STAGE(1, 0, 0); STAGE(1, 1, 1);
    __builtin_amdgcn_sched_barrier(0);
    asm volatile("s_waitcnt vmcnt(6)");      // T0 fully landed; 3 halves pending
    __builtin_amdgcn_sched_barrier(0);
    __builtin_amdgcn_s_barrier();

    for (int kt = 0; kt < 24; ++kt) {
        int buf = kt & 1;
        PHASE_A(buf, 0, kt + 1, 0, 1); ENDP();   // S1: A(kt+1).KH1
        PHASE_B(buf, 0, kt + 2, 1, 0); ENDP();   // S2: B(kt+2).KH0
        PHASE_A(buf, 1, kt + 2, 0, 0); ENDP();   // S3: A(kt+2).KH0
        PHASE_B(buf, 1, kt + 2, 1, 1); ENDV6();  // S4: B(kt+2).KH1 + vmcnt(6)
    }

    __syncthreads();   // full drain; LDS reused for reduction below

    // epilogue: score = xn2[row] + cn2[col] - 2*dot ; per-row (min1, idx1, min2)
    float* rv1 = (float*)ldsc;            // [256][4]
    float* rv2 = rv1 + 1024;              // [256][4]
    int*   ri1 = (int*)(rv1 + 2048);      // [256][4]

    float cnv[4];
#pragma unroll
    for (int n = 0; n < 4; ++n) cnv[n] = cn2[colBase + wc * 64 + n * 16 + c15];

#pragma unroll
    for (int m = 0; m < 8; ++m) {
#pragma unroll
        for (int j = 0; j < 4; ++j) {
            int rl = wr * 128 + m * 16 + g * 4 + j;
            float xn = xn2[rowBase + rl];
            float v1 = 3.402823466e38f, v2 = 3.402823466e38f; int i1 = 0x7fffffff;
#pragma unroll
            for (int n = 0; n < 4; ++n) {
                float s = xn + cnv[n] - 2.f * acc[m][n][j];
                int ci = colBase + wc * 64 + n * 16 + c15;
                if (s < v1 || (s == v1 && ci < i1)) { v2 = v1; v1 = s; i1 = ci; }
                else if (s < v2) v2 = s;
            }
#pragma unroll
            for (int off = 1; off < 16; off <<= 1) {
                float ov1 = __shfl_xor(v1, off);
                int   oi1 = __shfl_xor(i1, off);
                float ov2 = __shfl_xor(v2, off);
                if (ov1 < v1 || (ov1 == v1 && oi1 < i1)) {
                    v2 = fminf(v1, ov2); v1 = ov1; i1 = oi1;
                } else {
                    v2 = fminf(v2, ov1);
                }
            }
            if (c15 == 0) {
                rv1[rl * 4 + wc] = v1; rv2[rl * 4 + wc] = v2; ri1[rl * 4 + wc] = i1;
            }
        }
    }
    __syncthreads();
    if (tid < 256) {
        float v1 = 3.402823466e38f, v2 = 3.402823466e38f; int i1 = 0x7fffffff;
#pragma unroll
        for (int t = 0; t < 4; ++t) {
            float a1 = rv1[tid * 4 + t], a2 = rv2[tid * 4 + t];
            int   ai = ri1[tid * 4 + t];
            if (a1 < v1 || (a1 == v1 && ai < i1)) { v2 = fminf(v1, a2); v1 = a1; i1 = ai; }
            else { v2 = fminf(v2, a1); }
        }
        size_t o = (size_t)(rowBase + tid) * 16 + tileN;
        pV1[o] = v1; pV2[o] = v2; pI1[o] = i1;
    }
}

// ------------- combine per-tile partials -> idx + near-tie flag -------------
__global__ void combine_flag(const float* __restrict__ pV1, const float* __restrict__ pV2,
                             const int* __restrict__ pI1,
                             int* __restrict__ idx, float* __restrict__ idxF,
                             int* __restrict__ flag, float* __restrict__ vminOut) {
    int r = blockIdx.x * blockDim.x + threadIdx.x;
    if (r >= R_ROWS) return;
    float v1 = 3.402823466e38f, v2 = 3.402823466e38f; int i1 = 0x7fffffff;
    for (int t = 0; t < 16; ++t) {
        float a1 = pV1[(size_t)r * 16 + t];
        float a2 = pV2[(size_t)r * 16 + t];
        int   ai = pI1[(size_t)r * 16 + t];
        if (a1 < v1 || (a1 == v1 && ai < i1)) { v2 = fminf(v1, a2); v1 = a1; i1 = ai; }
        else { v2 = fminf(v2, a1); }
    }
    idx[r] = i1;
    idxF[r] = (float)i1;
    vminOut[r] = v1;
    flag[r] = (v2 - v1 < MARGIN) ? 1 : 0;
}

// ------------- exact f32 re-score of near-tie rows (candidate tiles only) ---
__launch_bounds__(256)
__global__ void refine_rows(const float* __restrict__ x, const float* __restrict__ cb,
                            const float* __restrict__ xn2, const float* __restrict__ cn2,
                            const float* __restrict__ pV1, const float* __restrict__ vmin,
                            const int* __restrict__ flag,
                            int* __restrict__ idx, float* __restrict__ idxF) {
    int r = blockIdx.x;
    if (flag[r] == 0) return;

    __shared__ float xs[DIM];
    __shared__ float sv[256];
    __shared__ int   si[256];
    for (int i = threadIdx.x; i < DIM; i += 256) xs[i] = x[(size_t)r * DIM + i];
    __syncthreads();

    float xn = xn2[r];
    float thr = vmin[r] + TILE_MARGIN;
    float v1 = 3.402823466e38f; int i1 = 0x7fffffff;

    for (int t = 0; t < 16; ++t) {
        if (pV1[(size_t)r * 16 + t] > thr) continue;
        int c = t * 256 + threadIdx.x;
        const float4* cr = reinterpret_cast<const float4*>(cb + (size_t)c * DIM);
        float dot = 0.f;
#pragma unroll 8
        for (int k = 0; k < DIM / 4; ++k) {
            float4 cv = cr[k];
            dot = fmaf(xs[k * 4 + 0], cv.x, dot);
            dot = fmaf(xs[k * 4 + 1], cv.y, dot);
            dot = fmaf(xs[k * 4 + 2], cv.z, dot);
            dot = fmaf(xs[k * 4 + 3], cv.w, dot);
        }
        float s = xn + cn2[c] - 2.f * dot;
        if (s < v1 || (s == v1 && c < i1)) { v1 = s; i1 = c; }
    }
    sv[threadIdx.x] = v1; si[threadIdx.x] = i1;
    __syncthreads();
    for (int o = 128; o; o >>= 1) {
        if (threadIdx.x < o) {
            float ov = sv[threadIdx.x + o]; int oi = si[threadIdx.x + o];
            if (ov < sv[threadIdx.x] || (ov == sv[threadIdx.x] && oi < si[threadIdx.x])) {
                sv[threadIdx.x] = ov; si[threadIdx.x] = oi;
            }
        }
        __syncthreads();
    }
    if (threadIdx.x == 0) { idx[r] = si[0]; idxF[r] = (float)si[0]; }
}

// ------------- combine per-tile argmin partials (fallback path) -------------
__global__ void argmin_combine(const float* __restrict__ pVal, const int* __restrict__ pIdx,
                               int* __restrict__ idxOut, float* __restrict__ idxFloatOut,
                               int nTiles) {
    int r = blockIdx.x * blockDim.x + threadIdx.x;
    if (r >= R_ROWS) return;
    float bv = 3.402823466e38f; int bi = 0;
    for (int t = 0; t < nTiles; t++) {
        float v = pVal[(size_t)r * nTiles + t];
        if (v < bv) { bv = v; bi = pIdx[(size_t)r * nTiles + t]; }
    }
    idxOut[r] = bi;
    idxFloatOut[r] = (float)bi;
}

// ------------- rotation trick, one wave per row -----------------------------
__global__ void rotate_rows(const float* __restrict__ x, const float* __restrict__ cb,
                            const int* __restrict__ idx, float* __restrict__ out,
                            float* __restrict__ lossPartial) {
    int gw = (blockIdx.x * blockDim.x + threadIdx.x) >> 6;
    int lane = threadIdx.x & 63;
    if (gw >= R_ROWS) return;

    const float4* x4 = reinterpret_cast<const float4*>(x + (size_t)gw * DIM);
    float4 xa = x4[lane], xb = x4[lane + 64];
    int ci = idx[gw];
    const float4* q4 = reinterpret_cast<const float4*>(cb + (size_t)ci * DIM);
    float4 qa = q4[lane], qb = q4[lane + 64];

    float xe[8] = {xa.x, xa.y, xa.z, xa.w, xb.x, xb.y, xb.z, xb.w};
    float qe[8] = {qa.x, qa.y, qa.z, qa.w, qb.x, qb.y, qb.z, qb.w};

    auto wsum = [&](float v) {
#pragma unroll
        for (int o = 32; o; o >>= 1) v += __shfl_xor(v, o);
        return v;
    };

    float lx = 0.f, lq = 0.f, ld = 0.f;
#pragma unroll
    for (int e = 0; e < 8; e++) {
        lx += xe[e] * xe[e];
        lq += qe[e] * qe[e];
        float d = xe[e] - qe[e];
        ld += d * d;
    }
    float sx2 = wsum(lx);
    float sq2 = wsum(lq);
    float lp  = wsum(ld);

    float nx = sqrtf(sx2), nq = sqrtf(sq2);
    float inx = 1.f / fmaxf(nx, 1e-6f);
    float inq = 1.f / fmaxf(nq, 1e-6f);

    float ue[8], qh[8], we[8];
    float lw = 0.f;
#pragma unroll
    for (int e = 0; e < 8; e++) {
        ue[e] = xe[e] * inx;
        qh[e] = qe[e] * inq;
        we[e] = ue[e] + qh[e];
        lw += we[e] * we[e];
    }
    float sw2 = wsum(lw);
    float inw = 1.f / fmaxf(sqrtf(sw2), 1e-6f);

    float lew = 0.f, leu = 0.f;
#pragma unroll
    for (int e = 0; e < 8; e++) {
        we[e] *= inw;
        lew += xe[e] * we[e];
        leu += xe[e] * ue[e];
    }
    float ew = wsum(lew);
    float eu = wsum(leu);

    float scale = nq / fmaxf(nx, 1e-6f);
    float oe[8];
#pragma unroll
    for (int e = 0; e < 8; e++)
        oe[e] = (xe[e] - 2.f * ew * we[e] + 2.f * eu * qh[e]) * scale;

    float4* o4 = reinterpret_cast<float4*>(out + (size_t)gw * DIM);
    o4[lane]      = make_float4(oe[0], oe[1], oe[2], oe[3]);
    o4[lane + 64] = make_float4(oe[4], oe[5], oe[6], oe[7]);

    if (lane == 0) lossPartial[gw] = lp;
}

// ------------- final loss reduction -----------------------------------------
__global__ void loss_reduce(const float* __restrict__ lp, float* __restrict__ outScalar) {
    __shared__ float red[256];
    float s = 0.f;
    for (int i = threadIdx.x; i < R_ROWS; i += 256) s += lp[i];
    red[threadIdx.x] = s;
    __syncthreads();
    for (int o = 128; o; o >>= 1) {
        if (threadIdx.x < o) red[threadIdx.x] += red[threadIdx.x + o];
        __syncthreads();
    }
    if (threadIdx.x == 0)
        outScalar[0] = 1.25f * red[0] / (float)(R_ROWS * DIM);
}

extern "C" void kernel_launch(void* const* d_in, const int* in_sizes, int n_in,
                              void* d_out, int out_size, void* d_ws, size_t ws_size,
                              hipStream_t stream) {
    const float* x      = (const float*)d_in[0];   // [8192, 512]
    const float* frozen = (const float*)d_in[1];   // [4096, 512]
    const float* weight = (const float*)d_in[2];   // [512, 512]
    float* out = (float*)d_out;

    // ---- workspace layout (MFMA path) ----
    char* p = (char*)d_ws;
    float* cb  = (float*)p;            p += (size_t)NCODES * DIM * 4;
    ushort* xh = (ushort*)p;           p += (size_t)R_ROWS * DIM * 2;
    ushort* xl = (ushort*)p;           p += (size_t)R_ROWS * DIM * 2;
    ushort* ch = (ushort*)p;           p += (size_t)NCODES * DIM * 2;
    ushort* cl = (ushort*)p;           p += (size_t)NCODES * DIM * 2;
    float* cn2 = (float*)p;            p += NCODES * 4;
    float* xn2 = (float*)p;            p += R_ROWS * 4;
    float* pV1 = (float*)p;            p += (size_t)R_ROWS * 16 * 4;
    float* pV2 = (float*)p;            p += (size_t)R_ROWS * 16 * 4;
    int*   pI1 = (int*)p;              p += (size_t)R_ROWS * 16 * 4;
    int*   idx = (int*)p;              p += R_ROWS * 4;
    int*   flg = (int*)p;              p += R_ROWS * 4;
    float* vmn = (float*)p;            p += R_ROWS * 4;
    float* lp  = (float*)p;            p += R_ROWS * 4;
    size_t need = (size_t)(p - (char*)d_ws);

    // 1. codebook = frozen @ W^T : M=4096, N=512, K=512 (f32, exact)
    //    64x64/4x4 config (r2-proven; r5's 128x64 retile regressed "rest" time)
    dim3 g1(DIM / 64, NCODES / 64);
    gemm_nt<64, 64, 4, 4, false><<<g1, 256, 0, stream>>>(
        frozen, weight, cb, nullptr, nullptr, nullptr, nullptr, NCODES, DIM, DIM);

    // 2. exact row norms
    rowsumsq<<<NCODES / 4, 256, 0, stream>>>(cb, cn2, NCODES);
    rowsumsq<<<R_ROWS / 4, 256, 0, stream>>>(x, xn2, R_ROWS);

    if (ws_size >= need) {
        // 3. split inputs into bf16 hi/lo
        split_bf16<<<(R_ROWS * DIM / 8) / 256, 256, 0, stream>>>(x, xh, xl, R_ROWS * DIM / 8);
        split_bf16<<<(NCODES * DIM / 8) / 256, 256, 0, stream>>>(cb, ch, cl, NCODES * DIM / 8);

        // 4. 8-phase 256^2 MFMA score GEMM + per-tile (min1, idx1, min2)
        score_mfma8<<<(R_ROWS / 256) * (NCODES / 256), 512, 0, stream>>>(
            xh, xl, ch, cl, xn2, cn2, pV1, pV2, pI1);

        // 5. combine + near-tie flag
        combine_flag<<<R_ROWS / 256, 256, 0, stream>>>(
            pV1, pV2, pI1, idx, out + (size_t)R_ROWS * DIM, flg, vmn);

        // 6. exact f32 re-score of flagged rows (candidate tiles only)
        refine_rows<<<R_ROWS, 256, 0, stream>>>(
            x, cb, xn2, cn2, pV1, vmn, flg, idx, out + (size_t)R_ROWS * DIM);
    } else {
        // fallback: proven f32 path
        float* fpV = (float*)((char*)d_ws + (size_t)NCODES * DIM * 4 + NCODES * 4 + R_ROWS * 4);
        int*   fpI = (int*)(fpV + (size_t)R_ROWS * 32);
        int*   fidx = (int*)(fpI + (size_t)R_ROWS * 32);
        float* flp = (float*)(fidx + R_ROWS);
        float* fcn2 = (float*)((char*)d_ws + (size_t)NCODES * DIM * 4);
        float* fxn2 = fcn2 + NCODES;
        rowsumsq<<<NCODES / 4, 256, 0, stream>>>(cb, fcn2, NCODES);
        rowsumsq<<<R_ROWS / 4, 256, 0, stream>>>(x, fxn2, R_ROWS);
        dim3 g2(NCODES / 128, R_ROWS / 128);
        gemm_nt<128, 128, 8, 8, true><<<g2, 256, 0, stream>>>(
            x, cb, nullptr, fxn2, fcn2, fpV, fpI, R_ROWS, NCODES, DIM);
        argmin_combine<<<R_ROWS / 256, 256, 0, stream>>>(
            fpV, fpI, fidx, out + (size_t)R_ROWS * DIM, NCODES / 128);
        rotate_rows<<<R_ROWS / 4, 256, 0, stream>>>(x, cb, fidx, out, flp);
        loss_reduce<<<1, 256, 0, stream>>>(flp, out + ((size_t)R_ROWS * DIM + R_ROWS));
        return;
    }

    // 7. rotation trick + loss
    rotate_rows<<<R_ROWS / 4, 256, 0, stream>>>(x, cb, idx, out, lp);
    loss_reduce<<<1, 256, 0, stream>>>(lp, out + ((size_t)R_ROWS * DIM + R_ROWS));
}